// Round 12
// baseline (258.196 us; speedup 1.0000x reference)
//
#include <hip/hip_runtime.h>
#include <hip/hip_fp16.h>

// DGCF single-layer, 2 routing iters (MI355X). fp32 in / fp32 out.
// R26: per-intent table slicing + XCD pinning on R24's fused structure.
// R25 post-mortem: zat 64.5us, FETCH 151MB = L2-CAPACITY bound (204MB of
// random 128B gathers vs 15.4MB tables; 4MB/XCD L2 -> 26% hit). Only the
// softmax couples intents; everything else is per-intent independent.
//  - Planar tables Yq[i][n][16] (= d0*X; fold is norm-invariant in zat and
//    exactly compensated in outk via d1rd0 = d1/d0) and Tq[i][n][16]:
//    1.92MB/slice -> one intent's A+B working set (3.84MB) FITS one XCD L2.
//  - zat pinned intent->XCD-pair (b&7, R14 decode): 32 nodes x 8 lanes
//    phase A (Z+norm -> LDS), phase B per-edge dot_i -> fp32 planar dotq.
//  - combine (new, streaming): softmax over 4 dots -> planar half sq,
//    bucket sums -> d1q + premultiplied d1rd0q.
//  - outk pinned: gathers only its 1.92MB Yq slice (L2-resident),
//    w = s * d1rd0q[t]; epilogue x d1q[n].
//  - prep needs d0 -> moved into scan_add2 dispatch (d0a from scan_local).
// Unchanged: rank-from-count atomic-free scatter, scans, LDS zn fusion.

#define NUSERS 30000
#define NN     60000
#define NNP    (NN + 1)
#define EE     800000
#define SCAN_B ((NN + 255) / 256)       // 235 scan blocks
#define EV_B   ((EE / 4 + 255) / 256)   // 782 int4 edge blocks
#define NW1_B  ((NN + 1 + 3) / 4)       // 15001 prep node blocks (incl zero row)
#define GPI    ((NN + 31) / 32)         // 1875 node-group32s per intent
#define PIN_B  ((((GPI + 1) / 2) * 8))  // 7504 pinned blocks (zat/outk)

__device__ __forceinline__ float getX(const float* __restrict__ Gu,
                                      const float* __restrict__ Gi,
                                      int n, int c) {
    return (n < NUSERS) ? Gu[n * 64 + c] : Gi[(n - NUSERS) * 64 + c];
}

__device__ __forceinline__ int clampN(int n) {
    return ((unsigned)n < (unsigned)NN) ? n : 0;
}

__device__ __forceinline__ __half2 bch2(float f) {
    return __builtin_bit_cast(__half2, f);
}

// ---- CSR build ----

__global__ void edge_count(const int* __restrict__ eh, int* __restrict__ deg0,
                           int* __restrict__ rank) {
    int e4 = (blockIdx.x * blockDim.x + threadIdx.x) * 4;
    if (e4 >= EE) return;
    int4 h = *(const int4*)(eh + e4);
    int4 r;
    r.x = atomicAdd(&deg0[clampN(h.x)], 1);
    r.y = atomicAdd(&deg0[clampN(h.y)], 1);
    r.z = atomicAdd(&deg0[clampN(h.z)], 1);
    r.w = atomicAdd(&deg0[clampN(h.w)], 1);
    *(int4*)(rank + e4) = r;
}

// In-block exclusive scan of 256 ints; also writes d0a (free: deg0 loaded).
__global__ void scan_local(const int* __restrict__ deg0, int* __restrict__ offsets,
                           int* __restrict__ bsum, float* __restrict__ d0a) {
    int gid = blockIdx.x * 256 + threadIdx.x;
    int lane = threadIdx.x & 63, w = threadIdx.x >> 6;
    int vdeg = (gid < NN) ? deg0[gid] : 0;
    if (gid < NN) d0a[gid] = rsqrtf(fmaxf(0.25f * (float)vdeg, 1e-30f));
    if (gid == NN) d0a[NN] = 0.f;               // zero row
    int x = vdeg;
    #pragma unroll
    for (int d = 1; d < 64; d <<= 1) {
        int y = __shfl_up(x, d, 64);
        if (lane >= d) x += y;
    }
    __shared__ int wsum[4];
    if (lane == 63) wsum[w] = x;
    __syncthreads();
    int wpre = 0;
    #pragma unroll
    for (int j = 0; j < 4; ++j) wpre += (j < w) ? wsum[j] : 0;
    int incl = x + wpre;
    if (gid < NN) offsets[gid] = incl - vdeg;
    if (threadIdx.x == 255) bsum[blockIdx.x] = incl;
}

// merged: scan_add2 (blocks [0,SCAN_B)) || prep planar tables (rest).
// prep: Yq[i][n][16] = half(d0[n]*X), Tq[i][n][16] = half(tanh(l2n(X)_i)).
__global__ void scanadd2_prep(int* __restrict__ offsets, const int* __restrict__ bsum,
                              const float* __restrict__ d0a,
                              const float* __restrict__ Gu, const float* __restrict__ Gi,
                              __half* __restrict__ Yq, __half* __restrict__ Tq) {
    if (blockIdx.x < SCAN_B) {
        int tid = threadIdx.x, lane = tid & 63, w = tid >> 6;
        int vv = (tid < SCAN_B) ? bsum[tid] : 0;
        int x = vv;
        #pragma unroll
        for (int d = 1; d < 64; d <<= 1) {
            int y = __shfl_up(x, d, 64);
            if (lane >= d) x += y;
        }
        __shared__ int wsum[4];
        __shared__ int bpre;
        if (lane == 63) wsum[w] = x;
        __syncthreads();
        int wpre = 0;
        #pragma unroll
        for (int j = 0; j < 4; ++j) wpre += (j < w) ? wsum[j] : 0;
        if (tid == blockIdx.x) bpre = x + wpre - vv;
        __syncthreads();
        int gid = blockIdx.x * 256 + tid;
        if (gid < NN) offsets[gid] += bpre;
        if (gid == 0) offsets[NN] = EE;
    } else {
        int n = (blockIdx.x - SCAN_B) * 4 + (threadIdx.x >> 6);
        if (n > NN) return;                     // zero row at n == NN
        int lane = threadIdx.x & 63;            // lane == channel
        int i = lane >> 4, cl = lane & 15;
        float x = (n < NN) ? getX(Gu, Gi, n, lane) : 0.f;
        float sx = x * x;
        #pragma unroll
        for (int m = 1; m < 16; m <<= 1) sx += __shfl_xor(sx, m, 64);  // intent group
        float invx = rsqrtf(fmaxf(sx, 1e-12f));
        float d0v = d0a[n];                     // broadcast (d0a[NN]=0)
        size_t a = ((size_t)i * NNP + n) * 16 + cl;
        Yq[a] = __float2half(d0v * x);
        Tq[a] = __float2half(tanhf(x * invx));
    }
}

// ---- scatter: atomic-free permute; ONE scattered 4B (tail) store/edge ----
__global__ void scatter(const int* __restrict__ eh, const int* __restrict__ et,
                        const int* __restrict__ rank, const int* __restrict__ offsets,
                        int* __restrict__ csr_tail) {
    int e4 = (blockIdx.x * 256 + threadIdx.x) * 4;
    if (e4 >= EE) return;
    int4 h = *(const int4*)(eh + e4);
    int4 t = *(const int4*)(et + e4);
    int4 r = *(const int4*)(rank + e4);
    int s0 = offsets[clampN(h.x)] + r.x;
    if ((unsigned)s0 < EE) csr_tail[s0] = clampN(t.x);
    int s1 = offsets[clampN(h.y)] + r.y;
    if ((unsigned)s1 < EE) csr_tail[s1] = clampN(t.y);
    int s2 = offsets[clampN(h.z)] + r.z;
    if ((unsigned)s2 < EE) csr_tail[s2] = clampN(t.z);
    int s3 = offsets[clampN(h.w)] + r.w;
    if ((unsigned)s3 < EE) csr_tail[s3] = clampN(t.w);
}

// ---- zat: pinned per-intent Z-accum + per-edge dot_i (32 nodes/block) ----
__global__ void zat(const int* __restrict__ offsets, const int* __restrict__ csr_tail,
                    const __half* __restrict__ Yq, const __half* __restrict__ Tq,
                    float* __restrict__ dotq) {
    __shared__ __half zn[32][24];       // 48B row stride (16B-aligned rows)
    __shared__ int soff[33];
    int b = blockIdx.x, tid = threadIdx.x;
    int xcd = b & 7;
    int i = xcd >> 1;                   // intent -> XCD pair (pinned)
    int g = (b >> 3) * 2 + (xcd & 1);
    if (g >= GPI) return;
    int n0 = g * 32;
    if (tid < 33) soff[tid] = offsets[n0 + tid];
    __syncthreads();

    // phase A: 32 nodes x 8 half2-lanes; Z = sum Yq[t] (d0 pre-folded), norm
    {
        int g8 = tid >> 3, cl = tid & 7;
        int s0 = soff[g8], s1 = soff[g8 + 1];
        const __half* Yi = Yq + (size_t)i * NNP * 16;
        float accx = 0.f, accy = 0.f;
        for (int base = s0; base < s1; base += 4) {
            #pragma unroll
            for (int u = 0; u < 4; ++u) {
                int kk = base + u;
                bool act = kk < s1;
                int kc = act ? kk : s0;          // in-bounds; deg >= 1 always
                int t = act ? csr_tail[kc] : NN; // NN = zero row
                __half2 y = *(const __half2*)(Yi + (size_t)t * 16 + cl * 2);
                float2 yf = __half22float2(y);
                accx += yf.x; accy += yf.y;
            }
        }
        float ss = accx * accx + accy * accy;
        ss += __shfl_xor(ss, 1, 64);
        ss += __shfl_xor(ss, 2, 64);
        ss += __shfl_xor(ss, 4, 64);             // 8-lane group = this intent
        float inv = rsqrtf(fmaxf(ss, 1e-12f));
        *(__half2*)&zn[g8][cl * 2] = __floats2half2_rn(accx * inv, accy * inv);
    }
    __syncthreads();

    // phase B: per-edge dot_i over the block's edge span (L2-resident Tq_i)
    int e0 = soff[0], e1 = soff[32];
    const __half* Ti = Tq + (size_t)i * NNP * 16;
    for (int k = e0 + tid; k < e1; k += 256) {
        int hl = 0;
        #pragma unroll
        for (int step = 16; step >= 1; step >>= 1)
            if (soff[hl + step] <= k) hl += step;  // hl caps at 31 (k < soff[32])
        int t = csr_tail[k];
        float4 ta = *(const float4*)(Ti + (size_t)t * 16);
        float4 tb = *(const float4*)(Ti + (size_t)t * 16 + 8);
        float4 za = *(const float4*)&zn[hl][0];
        float4 zb = *(const float4*)&zn[hl][8];
        __half2 acc = __floats2half2_rn(0.f, 0.f);
        acc = __hfma2(bch2(za.x), bch2(ta.x), acc);
        acc = __hfma2(bch2(za.y), bch2(ta.y), acc);
        acc = __hfma2(bch2(za.z), bch2(ta.z), acc);
        acc = __hfma2(bch2(za.w), bch2(ta.w), acc);
        acc = __hfma2(bch2(zb.x), bch2(tb.x), acc);
        acc = __hfma2(bch2(zb.y), bch2(tb.y), acc);
        acc = __hfma2(bch2(zb.z), bch2(tb.z), acc);
        acc = __hfma2(bch2(zb.w), bch2(tb.w), acc);
        float2 f = __half22float2(acc);
        dotq[(size_t)i * EE + k] = f.x + f.y;
    }
}

// ---- combine: softmax over 4 dots + bucket sums (wave per node) ----
__global__ void combine(const int* __restrict__ offsets, const float* __restrict__ dotq,
                        const float* __restrict__ d0a,
                        __half* __restrict__ sq, float* __restrict__ d1q,
                        float* __restrict__ d1rd0q) {
    int n = blockIdx.x * 4 + (threadIdx.x >> 6);
    if (n >= NN) return;
    int lane = threadIdx.x & 63;
    int s0 = offsets[n], s1 = offsets[n + 1];
    float sum0 = 0.f, sum1 = 0.f, sum2 = 0.f, sum3 = 0.f;
    for (int k = s0 + lane; k < s1; k += 64) {
        float v0 = dotq[k];
        float v1 = dotq[EE + k];
        float v2 = dotq[2 * EE + k];
        float v3 = dotq[3 * EE + k];
        float mx = fmaxf(fmaxf(v0, v1), fmaxf(v2, v3));
        float e0 = __expf(v0 - mx), e1 = __expf(v1 - mx);
        float e2 = __expf(v2 - mx), e3 = __expf(v3 - mx);
        float inv = 1.f / (e0 + e1 + e2 + e3);
        e0 *= inv; e1 *= inv; e2 *= inv; e3 *= inv;
        sq[k]          = __float2half(e0);
        sq[EE + k]     = __float2half(e1);
        sq[2 * EE + k] = __float2half(e2);
        sq[3 * EE + k] = __float2half(e3);
        sum0 += e0; sum1 += e1; sum2 += e2; sum3 += e3;
    }
    #pragma unroll
    for (int m = 1; m < 64; m <<= 1) {
        sum0 += __shfl_xor(sum0, m, 64);
        sum1 += __shfl_xor(sum1, m, 64);
        sum2 += __shfl_xor(sum2, m, 64);
        sum3 += __shfl_xor(sum3, m, 64);
    }
    if (lane < 4) {
        float ds = (lane == 0) ? sum0 : (lane == 1) ? sum1 : (lane == 2) ? sum2 : sum3;
        float d1 = rsqrtf(fmaxf(ds, 1e-30f));
        d1q[(size_t)lane * NNP + n] = d1;
        d1rd0q[(size_t)lane * NNP + n] = d1 / d0a[n];   // d1/d0 (deg>=1 -> d0a>0)
    }
}

// ---- outk: pinned per-intent Z2 gather + finalize (32 nodes/block) ----
__global__ void outk(const int* __restrict__ offsets, const int* __restrict__ csr_tail,
                     const __half* __restrict__ Yq, const __half* __restrict__ sq,
                     const float* __restrict__ d1q, const float* __restrict__ d1rd0q,
                     const float* __restrict__ Gu, const float* __restrict__ Gi,
                     float* __restrict__ out) {
    int b = blockIdx.x, tid = threadIdx.x;
    int xcd = b & 7;
    int i = xcd >> 1;                   // intent -> XCD pair (pinned, same as zat)
    int g = (b >> 3) * 2 + (xcd & 1);
    if (g >= GPI) return;
    int n = g * 32 + (tid >> 3);
    int cl = tid & 7;                   // half2-channel within intent
    int s0 = offsets[n], s1 = offsets[n + 1];
    const __half* Yi = Yq + (size_t)i * NNP * 16;
    const __half* si = sq + (size_t)i * EE;
    const float* w1 = d1rd0q + (size_t)i * NNP;
    float accx = 0.f, accy = 0.f;
    for (int base = s0; base < s1; base += 4) {
        #pragma unroll
        for (int u = 0; u < 4; ++u) {
            int kk = base + u;
            bool act = kk < s1;
            int kc = act ? kk : s0;              // in-bounds; deg >= 1 always
            int t = csr_tail[kc];
            float s = act ? __half2float(si[kc]) : 0.f;
            float w = s * w1[t];                 // s * d1[t]/d0[t]; Yq holds d0*X
            __half2 y = *(const __half2*)(Yi + (size_t)t * 16 + cl * 2);
            float2 yf = __half22float2(y);
            accx = fmaf(w, yf.x, accx);
            accy = fmaf(w, yf.y, accy);
        }
    }
    float d = d1q[(size_t)i * NNP + n];
    int ch = i * 16 + cl * 2;
    const float* xr = (n < NUSERS) ? (Gu + (size_t)n * 64 + ch)
                                   : (Gi + (size_t)(n - NUSERS) * 64 + ch);
    float2 x2 = *(const float2*)xr;
    float2 o;
    o.x = 0.5f * (x2.x + d * accx);
    o.y = 0.5f * (x2.y + d * accy);
    *(float2*)(out + (size_t)n * 64 + ch) = o;
}

// ---- launch ----

extern "C" void kernel_launch(void* const* d_in, const int* in_sizes, int n_in,
                              void* d_out, int out_size, void* d_ws, size_t ws_size,
                              hipStream_t stream) {
    const float* Gu = (const float*)d_in[0];
    const float* Gi = (const float*)d_in[1];
    const int* eh = (const int*)d_in[2];
    const int* et = (const int*)d_in[3];
    float* out = (float*)d_out;

    char* p = (char*)d_ws;
    float*  dotq     = (float*)p;      p += (size_t)EE * 4 * 4;       // 12.8 MB
    __half* sq       = (__half*)p;     p += (size_t)EE * 4 * 2;       // 6.4 MB
    int*    csr_tail = (int*)p;        p += (size_t)EE * 4;           // 3.2 MB
    int*    rank     = (int*)p;        p += (size_t)EE * 4;           // 3.2 MB
    int*    offsets  = (int*)p;        p += ((size_t)NNP * 4 + 15) / 16 * 16;
    int*    deg0     = (int*)p;        p += (size_t)NN * 4;
    int*    bsum     = (int*)p;        p += ((size_t)SCAN_B * 4 + 15) / 16 * 16;
    float*  d0a      = (float*)p;      p += ((size_t)NNP * 4 + 15) / 16 * 16;
    float*  d1q      = (float*)p;      p += (size_t)4 * NNP * 4;      // 0.96 MB
    float*  d1rd0q   = (float*)p;      p += (size_t)4 * NNP * 4;      // 0.96 MB
    __half* Yq       = (__half*)p;     p += (size_t)4 * NNP * 16 * 2; // 7.68 MB
    __half* Tq       = (__half*)p;     // 7.68 MB -> total ~43 MB

    // CSR build
    hipMemsetAsync(deg0, 0, NN * sizeof(int), stream);
    edge_count<<<EV_B, 256, 0, stream>>>(eh, deg0, rank);
    scan_local<<<SCAN_B, 256, 0, stream>>>(deg0, offsets, bsum, d0a);
    // scan finish || planar per-intent table prep (needs d0a)
    scanadd2_prep<<<SCAN_B + NW1_B, 256, 0, stream>>>(offsets, bsum, d0a,
                                                      Gu, Gi, Yq, Tq);
    scatter<<<EV_B, 256, 0, stream>>>(eh, et, rank, offsets, csr_tail);

    // iter 0: pinned per-intent Z + dots (L2-resident slices)
    zat<<<PIN_B, 256, 0, stream>>>(offsets, csr_tail, Yq, Tq, dotq);

    // softmax + bucket sums (streaming)
    combine<<<(NN + 3) / 4, 256, 0, stream>>>(offsets, dotq, d0a, sq, d1q, d1rd0q);

    // iter 1: pinned per-intent propagate + finalize
    outk<<<PIN_B, 256, 0, stream>>>(offsets, csr_tail, Yq, sq, d1q, d1rd0q,
                                    Gu, Gi, out);
}

// Round 13
// 245.629 us; speedup vs baseline: 1.0512x; 1.0512x over previous
//
#include <hip/hip_runtime.h>
#include <hip/hip_fp16.h>

// DGCF single-layer, 2 routing iters (MI355X). fp32 in / fp32 out.
// R27: hybrid of R26-zat + R25-outk.
// R26 post-mortem (+23us): per-intent pinned outk re-introduced 4
// visits/edge (3.2M 32B-slice gathers -> 60us, FETCH 42MB, HBM 12% =
// latency-bound) -- the exact disease R19 cured. zat DID improve (off
// top-5, <59us vs 64.5 in R25).
// Hybrid:
//  - zat: R26 pinned per-intent planar form (Yq/Tq slices L2-resident),
//    phase B stores HALF planar dots (6.4MB; half-dot storage verified
//    pre-R21 at same absmax).
//  - combine: planar dots -> softmax -> INTERLEAVED s4 + dcol1[n][4]
//    (= R19's verified sm_dcol_y1 minus the Y1i row).
//  - outk: R25 verbatim single-visit form (2 nodes x 32 lanes, one full
//    128B interleaved Xh[t] row/edge, w = s*d1[t], fp32).
//  - prep additionally writes interleaved Xh[n][64] (coalesced).
// Unchanged: rank-from-count scatter, scans, d0a from scan_local.

#define NUSERS 30000
#define NN     60000
#define NNP    (NN + 1)
#define EE     800000
#define SCAN_B ((NN + 255) / 256)       // 235 scan blocks
#define EV_B   ((EE / 4 + 255) / 256)   // 782 int4 edge blocks
#define NW1_B  ((NN + 1 + 3) / 4)       // 15001 prep node blocks (incl zero row)
#define NW_B   ((NN + 3) / 4)           // 15000 combine blocks
#define N8_B   (NN / 8)                 // 7500 outk blocks (8 nodes; 8 | NN)
#define GPI    ((NN + 31) / 32)         // 1875 node-group32s per intent
#define PIN_B  ((((GPI + 1) / 2) * 8))  // 7504 pinned zat blocks

__device__ __forceinline__ float getX(const float* __restrict__ Gu,
                                      const float* __restrict__ Gi,
                                      int n, int c) {
    return (n < NUSERS) ? Gu[n * 64 + c] : Gi[(n - NUSERS) * 64 + c];
}

__device__ __forceinline__ int clampN(int n) {
    return ((unsigned)n < (unsigned)NN) ? n : 0;
}

__device__ __forceinline__ __half2 bch2(float f) {
    return __builtin_bit_cast(__half2, f);
}

// ---- CSR build ----

__global__ void edge_count(const int* __restrict__ eh, int* __restrict__ deg0,
                           int* __restrict__ rank) {
    int e4 = (blockIdx.x * blockDim.x + threadIdx.x) * 4;
    if (e4 >= EE) return;
    int4 h = *(const int4*)(eh + e4);
    int4 r;
    r.x = atomicAdd(&deg0[clampN(h.x)], 1);
    r.y = atomicAdd(&deg0[clampN(h.y)], 1);
    r.z = atomicAdd(&deg0[clampN(h.z)], 1);
    r.w = atomicAdd(&deg0[clampN(h.w)], 1);
    *(int4*)(rank + e4) = r;
}

// In-block exclusive scan of 256 ints; also writes d0a (free: deg0 loaded).
__global__ void scan_local(const int* __restrict__ deg0, int* __restrict__ offsets,
                           int* __restrict__ bsum, float* __restrict__ d0a) {
    int gid = blockIdx.x * 256 + threadIdx.x;
    int lane = threadIdx.x & 63, w = threadIdx.x >> 6;
    int vdeg = (gid < NN) ? deg0[gid] : 0;
    if (gid < NN) d0a[gid] = rsqrtf(fmaxf(0.25f * (float)vdeg, 1e-30f));
    if (gid == NN) d0a[NN] = 0.f;               // zero row
    int x = vdeg;
    #pragma unroll
    for (int d = 1; d < 64; d <<= 1) {
        int y = __shfl_up(x, d, 64);
        if (lane >= d) x += y;
    }
    __shared__ int wsum[4];
    if (lane == 63) wsum[w] = x;
    __syncthreads();
    int wpre = 0;
    #pragma unroll
    for (int j = 0; j < 4; ++j) wpre += (j < w) ? wsum[j] : 0;
    int incl = x + wpre;
    if (gid < NN) offsets[gid] = incl - vdeg;
    if (threadIdx.x == 255) bsum[blockIdx.x] = incl;
}

// merged: scan_add2 (blocks [0,SCAN_B)) || prep tables (rest).
// prep: planar Yq[i][n][16] = d0*X, Tq[i][n][16] = tanh; interleaved
// Xh[n][64] = X (for outk's single-visit full-line gathers).
__global__ void scanadd2_prep(int* __restrict__ offsets, const int* __restrict__ bsum,
                              const float* __restrict__ d0a,
                              const float* __restrict__ Gu, const float* __restrict__ Gi,
                              __half* __restrict__ Yq, __half* __restrict__ Tq,
                              __half* __restrict__ Xh) {
    if (blockIdx.x < SCAN_B) {
        int tid = threadIdx.x, lane = tid & 63, w = tid >> 6;
        int vv = (tid < SCAN_B) ? bsum[tid] : 0;
        int x = vv;
        #pragma unroll
        for (int d = 1; d < 64; d <<= 1) {
            int y = __shfl_up(x, d, 64);
            if (lane >= d) x += y;
        }
        __shared__ int wsum[4];
        __shared__ int bpre;
        if (lane == 63) wsum[w] = x;
        __syncthreads();
        int wpre = 0;
        #pragma unroll
        for (int j = 0; j < 4; ++j) wpre += (j < w) ? wsum[j] : 0;
        if (tid == blockIdx.x) bpre = x + wpre - vv;
        __syncthreads();
        int gid = blockIdx.x * 256 + tid;
        if (gid < NN) offsets[gid] += bpre;
        if (gid == 0) offsets[NN] = EE;
    } else {
        int n = (blockIdx.x - SCAN_B) * 4 + (threadIdx.x >> 6);
        if (n > NN) return;                     // zero row at n == NN
        int lane = threadIdx.x & 63;            // lane == channel
        int i = lane >> 4, cl = lane & 15;
        float x = (n < NN) ? getX(Gu, Gi, n, lane) : 0.f;
        float sx = x * x;
        #pragma unroll
        for (int m = 1; m < 16; m <<= 1) sx += __shfl_xor(sx, m, 64);  // intent group
        float invx = rsqrtf(fmaxf(sx, 1e-12f));
        float d0v = d0a[n];                     // broadcast (d0a[NN]=0)
        size_t a = ((size_t)i * NNP + n) * 16 + cl;
        Yq[a] = __float2half(d0v * x);
        Tq[a] = __float2half(tanhf(x * invx));
        Xh[(size_t)n * 64 + lane] = __float2half(x);
    }
}

// ---- scatter: atomic-free permute; ONE scattered 4B (tail) store/edge ----
__global__ void scatter(const int* __restrict__ eh, const int* __restrict__ et,
                        const int* __restrict__ rank, const int* __restrict__ offsets,
                        int* __restrict__ csr_tail) {
    int e4 = (blockIdx.x * 256 + threadIdx.x) * 4;
    if (e4 >= EE) return;
    int4 h = *(const int4*)(eh + e4);
    int4 t = *(const int4*)(et + e4);
    int4 r = *(const int4*)(rank + e4);
    int s0 = offsets[clampN(h.x)] + r.x;
    if ((unsigned)s0 < EE) csr_tail[s0] = clampN(t.x);
    int s1 = offsets[clampN(h.y)] + r.y;
    if ((unsigned)s1 < EE) csr_tail[s1] = clampN(t.y);
    int s2 = offsets[clampN(h.z)] + r.z;
    if ((unsigned)s2 < EE) csr_tail[s2] = clampN(t.z);
    int s3 = offsets[clampN(h.w)] + r.w;
    if ((unsigned)s3 < EE) csr_tail[s3] = clampN(t.w);
}

// ---- zat: pinned per-intent Z-accum + per-edge dot_i (32 nodes/block) ----
__global__ void zat(const int* __restrict__ offsets, const int* __restrict__ csr_tail,
                    const __half* __restrict__ Yq, const __half* __restrict__ Tq,
                    __half* __restrict__ dotq) {
    __shared__ __half zn[32][24];       // 48B row stride (16B-aligned rows)
    __shared__ int soff[33];
    int b = blockIdx.x, tid = threadIdx.x;
    int xcd = b & 7;
    int i = xcd >> 1;                   // intent -> XCD pair (pinned)
    int g = (b >> 3) * 2 + (xcd & 1);
    if (g >= GPI) return;
    int n0 = g * 32;
    if (tid < 33) soff[tid] = offsets[n0 + tid];
    __syncthreads();

    // phase A: 32 nodes x 8 half2-lanes; Z = sum Yq[t] (d0 pre-folded), norm
    {
        int g8 = tid >> 3, cl = tid & 7;
        int s0 = soff[g8], s1 = soff[g8 + 1];
        const __half* Yi = Yq + (size_t)i * NNP * 16;
        float accx = 0.f, accy = 0.f;
        for (int base = s0; base < s1; base += 4) {
            #pragma unroll
            for (int u = 0; u < 4; ++u) {
                int kk = base + u;
                bool act = kk < s1;
                int kc = act ? kk : s0;          // in-bounds; deg >= 1 always
                int t = act ? csr_tail[kc] : NN; // NN = zero row
                __half2 y = *(const __half2*)(Yi + (size_t)t * 16 + cl * 2);
                float2 yf = __half22float2(y);
                accx += yf.x; accy += yf.y;
            }
        }
        float ss = accx * accx + accy * accy;
        ss += __shfl_xor(ss, 1, 64);
        ss += __shfl_xor(ss, 2, 64);
        ss += __shfl_xor(ss, 4, 64);             // 8-lane group = this intent
        float inv = rsqrtf(fmaxf(ss, 1e-12f));
        *(__half2*)&zn[g8][cl * 2] = __floats2half2_rn(accx * inv, accy * inv);
    }
    __syncthreads();

    // phase B: per-edge dot_i over the block's edge span (L2-resident Tq_i)
    int e0 = soff[0], e1 = soff[32];
    const __half* Ti = Tq + (size_t)i * NNP * 16;
    for (int k = e0 + tid; k < e1; k += 256) {
        int hl = 0;
        #pragma unroll
        for (int step = 16; step >= 1; step >>= 1)
            if (soff[hl + step] <= k) hl += step;  // hl caps at 31 (k < soff[32])
        int t = csr_tail[k];
        float4 ta = *(const float4*)(Ti + (size_t)t * 16);
        float4 tb = *(const float4*)(Ti + (size_t)t * 16 + 8);
        float4 za = *(const float4*)&zn[hl][0];
        float4 zb = *(const float4*)&zn[hl][8];
        __half2 acc = __floats2half2_rn(0.f, 0.f);
        acc = __hfma2(bch2(za.x), bch2(ta.x), acc);
        acc = __hfma2(bch2(za.y), bch2(ta.y), acc);
        acc = __hfma2(bch2(za.z), bch2(ta.z), acc);
        acc = __hfma2(bch2(za.w), bch2(ta.w), acc);
        acc = __hfma2(bch2(zb.x), bch2(tb.x), acc);
        acc = __hfma2(bch2(zb.y), bch2(tb.y), acc);
        acc = __hfma2(bch2(zb.z), bch2(tb.z), acc);
        acc = __hfma2(bch2(zb.w), bch2(tb.w), acc);
        float2 f = __half22float2(acc);
        dotq[(size_t)i * EE + k] = __float2half(f.x + f.y);
    }
}

// ---- combine: softmax over 4 planar dots -> interleaved s4 + dcol1 ----
// (R19's verified sm_dcol_y1 structure minus the Y1i row.)
__global__ void combine(const int* __restrict__ offsets, const __half* __restrict__ dotq,
                        __half* __restrict__ s4, float* __restrict__ dcol1) {
    int n = blockIdx.x * 4 + (threadIdx.x >> 6);
    if (n >= NN) return;
    int lane = threadIdx.x & 63;
    int s0 = offsets[n], s1 = offsets[n + 1];
    float sum0 = 0.f, sum1 = 0.f, sum2 = 0.f, sum3 = 0.f;
    for (int k = s0 + lane; k < s1; k += 64) {
        float v0 = __half2float(dotq[k]);
        float v1 = __half2float(dotq[EE + k]);
        float v2 = __half2float(dotq[2 * EE + k]);
        float v3 = __half2float(dotq[3 * EE + k]);
        float mx = fmaxf(fmaxf(v0, v1), fmaxf(v2, v3));
        float e0 = __expf(v0 - mx), e1 = __expf(v1 - mx);
        float e2 = __expf(v2 - mx), e3 = __expf(v3 - mx);
        float inv = 1.f / (e0 + e1 + e2 + e3);
        e0 *= inv; e1 *= inv; e2 *= inv; e3 *= inv;
        __half2 q01 = __floats2half2_rn(e0, e1);
        __half2 q23 = __floats2half2_rn(e2, e3);
        int2 st;
        st.x = __builtin_bit_cast(int, q01);
        st.y = __builtin_bit_cast(int, q23);
        *(int2*)(s4 + (size_t)k * 4) = st;
        sum0 += e0; sum1 += e1; sum2 += e2; sum3 += e3;
    }
    #pragma unroll
    for (int m = 1; m < 64; m <<= 1) {
        sum0 += __shfl_xor(sum0, m, 64);
        sum1 += __shfl_xor(sum1, m, 64);
        sum2 += __shfl_xor(sum2, m, 64);
        sum3 += __shfl_xor(sum3, m, 64);
    }
    if (lane < 4) {
        float ds = (lane == 0) ? sum0 : (lane == 1) ? sum1 : (lane == 2) ? sum2 : sum3;
        dcol1[n * 4 + lane] = rsqrtf(fmaxf(ds, 1e-30f));
    }
}

// ---- output pass: Z2 gather + finalize (R25 verified form) ----
// wave = 2 nodes x 32 half2-ch lanes. Per edge: broadcast csr_tail + s4 +
// dcol1[t] (L2-resident); 32 lanes gather one full 128B Xh row; single
// visit per edge; fp32 weights; float2 store.
__global__ void outk(const int* __restrict__ offsets, const int* __restrict__ csr_tail,
                     const __half* __restrict__ Xh, const __half* __restrict__ s4,
                     const float* __restrict__ dcol1,
                     const float* __restrict__ Gu, const float* __restrict__ Gi,
                     float* __restrict__ out) {
    int tid = threadIdx.x;
    int n = blockIdx.x * 8 + (tid >> 5);
    if (n >= NN) return;
    int cc = tid & 31;                           // half2-channel (2cc, 2cc+1)
    int i = cc >> 3;                             // intent of this lane's channels
    int s0 = offsets[n], s1 = offsets[n + 1];
    float accx = 0.f, accy = 0.f;
    for (int base = s0; base < s1; base += 4) {
        #pragma unroll
        for (int u = 0; u < 4; ++u) {
            int kk = base + u;
            bool act = kk < s1;
            int kc = act ? kk : s0;              // in-bounds; deg >= 1 always
            int t = csr_tail[kc];
            int2 raw = *(const int2*)(s4 + (size_t)kc * 4);
            int word = (cc & 16) ? raw.y : raw.x;
            unsigned short us = (unsigned short)(word >> ((cc & 8) ? 16 : 0));
            float s = act ? __half2float(__builtin_bit_cast(__half, us)) : 0.f;
            float w = s * dcol1[t * 4 + i];      // s * d1[tail][intent]
            __half2 y = *(const __half2*)(Xh + (size_t)t * 64 + cc * 2);
            float2 yf = __half22float2(y);
            accx = fmaf(w, yf.x, accx);
            accy = fmaf(w, yf.y, accy);
        }
    }
    float d = dcol1[n * 4 + i];
    int ch = cc * 2;
    const float* xr = (n < NUSERS) ? (Gu + (size_t)n * 64 + ch)
                                   : (Gi + (size_t)(n - NUSERS) * 64 + ch);
    float2 x2 = *(const float2*)xr;
    float2 o;
    o.x = 0.5f * (x2.x + d * accx);
    o.y = 0.5f * (x2.y + d * accy);
    *(float2*)(out + (size_t)n * 64 + ch) = o;
}

// ---- launch ----

extern "C" void kernel_launch(void* const* d_in, const int* in_sizes, int n_in,
                              void* d_out, int out_size, void* d_ws, size_t ws_size,
                              hipStream_t stream) {
    const float* Gu = (const float*)d_in[0];
    const float* Gi = (const float*)d_in[1];
    const int* eh = (const int*)d_in[2];
    const int* et = (const int*)d_in[3];
    float* out = (float*)d_out;

    char* p = (char*)d_ws;
    __half* dotq     = (__half*)p;     p += (size_t)EE * 4 * 2;       // 6.4 MB
    __half* s4       = (__half*)p;     p += (size_t)EE * 4 * 2;       // 6.4 MB
    int*    csr_tail = (int*)p;        p += (size_t)EE * 4;           // 3.2 MB
    int*    rank     = (int*)p;        p += (size_t)EE * 4;           // 3.2 MB
    int*    offsets  = (int*)p;        p += ((size_t)NNP * 4 + 15) / 16 * 16;
    int*    deg0     = (int*)p;        p += (size_t)NN * 4;
    int*    bsum     = (int*)p;        p += ((size_t)SCAN_B * 4 + 15) / 16 * 16;
    float*  d0a      = (float*)p;      p += ((size_t)NNP * 4 + 15) / 16 * 16;
    float*  dcol1    = (float*)p;      p += (size_t)NN * 4 * 4;       // 960 KB
    __half* Yq       = (__half*)p;     p += (size_t)4 * NNP * 16 * 2; // 7.68 MB
    __half* Tq       = (__half*)p;     p += (size_t)4 * NNP * 16 * 2; // 7.68 MB
    __half* Xh       = (__half*)p;     // NNP*64*2 = 7.68 MB -> total ~46 MB

    // CSR build
    hipMemsetAsync(deg0, 0, NN * sizeof(int), stream);
    edge_count<<<EV_B, 256, 0, stream>>>(eh, deg0, rank);
    scan_local<<<SCAN_B, 256, 0, stream>>>(deg0, offsets, bsum, d0a);
    // scan finish || table prep (planar Yq/Tq for zat, interleaved Xh for outk)
    scanadd2_prep<<<SCAN_B + NW1_B, 256, 0, stream>>>(offsets, bsum, d0a,
                                                      Gu, Gi, Yq, Tq, Xh);
    scatter<<<EV_B, 256, 0, stream>>>(eh, et, rank, offsets, csr_tail);

    // iter 0: pinned per-intent Z + dots (L2-resident slices), half dots
    zat<<<PIN_B, 256, 0, stream>>>(offsets, csr_tail, Yq, Tq, dotq);

    // softmax -> interleaved s4 + dcol1 (streaming)
    combine<<<NW_B, 256, 0, stream>>>(offsets, dotq, s4, dcol1);

    // iter 1: single-visit full-line propagate + finalize (R25 form)
    outk<<<N8_B, 256, 0, stream>>>(offsets, csr_tail, Xh, s4, dcol1, Gu, Gi, out);
}